// Round 17
// baseline (82.528 us; speedup 1.0000x reference)
//
#include <hip/hip_runtime.h>

typedef unsigned int u32;
typedef unsigned long long u64;

#define BB 16
#define LL 8192
#define CC 512
#define KK 64
#define LCH 256          // L-chunks per batch
#define LPB 32           // rows per chunk (bitmask width)
#define THRESH 2.1f      // survivors/col: mean~146 sigma~12 -> >=64 w/ ~7 sigma margin

// intra-wave LDS ordering fence (rule 18: sched_barrier after asm lgkmcnt)
#define WAVE_FENCE()                                            \
  do {                                                          \
    asm volatile("s_waitcnt lgkmcnt(0)" ::: "memory");          \
    __builtin_amdgcn_sched_barrier(0);                          \
  } while (0)

// ---- order-preserving fp32 <-> u32 key transforms ----
__device__ __forceinline__ u32 flip_bits(u32 u) {
  return u ^ ((u & 0x80000000u) ? 0xFFFFFFFFu : 0x80000000u);
}
__device__ __forceinline__ u32 unflip_bits(u32 f) {
  return (f & 0x80000000u) ? (f ^ 0x80000000u) : ~f;
}
__device__ __forceinline__ u64 u64max(u64 a, u64 b) { return a > b ? a : b; }

// ---------------- Kernel A (R2-proven, at roofline ~40us): DO NOT TOUCH ----------------
__global__ __launch_bounds__(128) void kbitmask(const float* __restrict__ x,
                                                u32* __restrict__ bm) {
  int blk = blockIdx.x;
  int b = blk >> 8;
  int chunk = blk & (LCH - 1);
  int t = threadIdx.x;
  const float4* p =
      reinterpret_cast<const float4*>(x + ((size_t)b * LL + (size_t)chunk * LPB) * CC) + t;
  u32 m0 = 0, m1 = 0, m2 = 0, m3 = 0;
#pragma unroll
  for (int i = 0; i < LPB; ++i) {
    float4 v = p[(size_t)i * (CC / 4)];
    m0 |= ((u32)(v.x > THRESH)) << i;
    m1 |= ((u32)(v.y > THRESH)) << i;
    m2 |= ((u32)(v.z > THRESH)) << i;
    m3 |= ((u32)(v.w > THRESH)) << i;
  }
  uint4* dst = reinterpret_cast<uint4*>(bm + (size_t)(b * LCH + chunk) * CC) + t;
  *dst = make_uint4(m0, m1, m2, m3);
}

// ---------------- Kernel B: wave-per-column, barrier-free select ----------------
// R16 crashed on a ctz guard bug: `mm | (~mm & 1)` ORs BIT 0, destroying the
// lowest-set-bit position for any mm with bit0 clear -> duplicate rows ->
// >64 selected -> OOB out[] write. Fix: OR the TOP bit (never affects ctz of
// a nonzero low bit); invalid slots (mm==0) are masked out of vbits anyway.
// Structure (R16): block = 16 waves = 16 cols; ONE __syncthreads (coalesced
// mask staging); per wave: lane owns 128 rows, <=16 static slots, one batched
// gather, keys in registers, histogram select in wave-private LDS, row-order
// output. Guards -> wave-local exact slow path.
__global__ __launch_bounds__(1024) void kselect(const float* __restrict__ x,
                                                const u32* __restrict__ bm,
                                                float* __restrict__ out,
                                                int force_slow) {
  __shared__ u32 M[16 * 260];     // [cc][chunk], stride 260 (16B-aligned rows)
  __shared__ u32 H[16 * 256];     // per-wave 256-bucket histogram
  __shared__ u64 cand[16 * 64];   // per-wave boundary-bucket keys
  __shared__ u32 ccnt[16];
  int t = threadIdx.x;
  int lane = t & 63;
  int w = t >> 6;
  int bid = blockIdx.x;
  int b = bid >> 5;
  int c0 = (bid & 31) * 16;
  int c = c0 + w;                 // this wave's column
  const float* colp = x + (size_t)b * LL * CC + c;

  // ---- staged coalesced mask read (the ONE cross-wave phase) ----
  if (!force_slow) {
#pragma unroll
    for (int it = 0; it < 4; ++it) {
      int idx = it * 1024 + t;
      int cc = idx & 15;
      int chunk = idx >> 4;       // 0..255
      M[cc * 260 + chunk] = bm[((size_t)b * LCH + (u32)chunk) * CC + (c0 + cc)];
    }
  }
  __syncthreads();

  bool bad = (force_slow != 0);
  u64 key_[16];
  u32 vbits = 0;
  u32 cb = 0, need = 0;

  if (!bad) {
    // ---- per-lane mask words: rows 128*lane .. 128*lane+127 ----
    uint4 mw = *reinterpret_cast<const uint4*>(&M[w * 260 + 4 * lane]);
    u64 m01 = (u64)mw.x | ((u64)mw.y << 32);   // rows +0..63
    u64 m23 = (u64)mw.z | ((u64)mw.w << 32);   // rows +64..127
    u32 rows_[16];
    // ---- static 16-slot extraction (P(>16 per 128 rows) ~ 1e-11/lane) ----
#pragma unroll
    for (int s = 0; s < 16; ++s) {
      bool use01 = (m01 != 0ull);
      u64 mm = use01 ? m01 : m23;
      bool valid = (mm != 0ull);
      // OR the TOP bit: safe ctz guard (does not perturb lowest set bit).
      u32 p = (u32)__builtin_ctzll(mm | 0x8000000000000000ull);
      rows_[s] = (u32)(128 * lane) + (use01 ? 0u : 64u) + p;
      vbits |= (valid ? 1u : 0u) << s;
      if (use01) m01 &= m01 - 1; else m23 &= m23 - 1;
    }
    if ((m01 | m23) != 0ull) bad = true;  // slot overflow
    // ---- one batched gather round ----
    float vals_[16];
#pragma unroll
    for (int s = 0; s < 16; ++s)
      vals_[s] = ((vbits >> s) & 1u)
                     ? __builtin_nontemporal_load(colp + (size_t)rows_[s] * CC)
                     : 0.0f;
    __builtin_amdgcn_sched_barrier(0);
    // ---- keys + wave-private histogram ----
    u32* Hw = H + w * 256;
#pragma unroll
    for (int j = 0; j < 4; ++j) Hw[4 * lane + j] = 0;
    WAVE_FENCE();
#pragma unroll
    for (int s = 0; s < 16; ++s) {
      u32 top = flip_bits(__float_as_uint(vals_[s]));
      key_[s] = (((u64)top) << 32) | rows_[s];
      if ((vbits >> s) & 1u) {
        if (top >= 0xC1800000u) bad = true;  // value >= 16: bucket would wrap
        atomicAdd(&Hw[(top >> 17) & 0xFFu], 1u);
      }
    }
    WAVE_FENCE();
    // ---- suffix scan over 256 buckets (4/lane + shfl) ----
    u32 h0 = Hw[4 * lane], h1 = Hw[4 * lane + 1], h2 = Hw[4 * lane + 2], h3 = Hw[4 * lane + 3];
    u32 p4 = h0 + h1 + h2 + h3;
    u32 sfx = p4;
#pragma unroll
    for (int d = 1; d < 64; d <<= 1) {
      u32 o = __shfl_down(sfx, d, 64);
      if (lane + d < 64) sfx += o;
    }
    u32 above_l = sfx - p4;          // keys in buckets of lanes > me
    u32 S3 = above_l + h3;           // S[4l+3]
    u32 S2 = S3 + h2;
    u32 S1 = S2 + h1;
    u32 S0 = S1 + h0;                // S[4l] = #keys with bucket >= 4l
    // cutoff bucket cb = largest k with S[k] >= KK
    int iloc = (S3 >= (u32)KK) ? 3 : (S2 >= (u32)KK) ? 2 : (S1 >= (u32)KK) ? 1 : (S0 >= (u32)KK) ? 0 : -1;
    u64 balv = __ballot(iloc >= 0);
    if (balv == 0ull) {
      bad = true;                    // fewer than 64 survivors
    } else {
      int hl = 63 - (int)__builtin_clzll(balv);
      u32 myk = (u32)(4 * lane + (iloc < 0 ? 0 : iloc));
      u32 Ssel = (iloc == 3) ? S3 : (iloc == 2) ? S2 : (iloc == 1) ? S1 : S0;
      u32 hsel = (iloc == 3) ? h3 : (iloc == 2) ? h2 : (iloc == 1) ? h1 : h0;
      cb = __shfl(myk, hl, 64);
      u32 S_cb = __shfl(Ssel, hl, 64);
      u32 h_cb = __shfl(hsel, hl, 64);
      need = (u32)KK - (S_cb - h_cb);  // boundary picks; >=1 by maximality of cb
    }
    // ---- boundary bucket resolution ----
    if (lane == 0) ccnt[w] = 0;
    WAVE_FENCE();
    u32 bnd = 0;
#pragma unroll
    for (int s = 0; s < 16; ++s) {
      if (((vbits >> s) & 1u) && (((u32)(key_[s] >> 49) & 0xFFu) == cb)) {
        u32 ci = atomicAdd(&ccnt[w], 1u);
        if (ci < 64u) cand[w * 64 + ci] = key_[s];
        else bad = true;
        bnd |= 1u << s;
      }
    }
    WAVE_FENCE();
    u32 nc = ccnt[w];
    if (nc > 64u) nc = 64u;
    // ---- selection + row-order output ----
    u32 selbits = 0;
#pragma unroll
    for (int s = 0; s < 16; ++s) {
      bool sel = false;
      if ((vbits >> s) & 1u) {
        u32 bkt = (u32)(key_[s] >> 49) & 0xFFu;
        if (bkt > cb) sel = true;
        else if ((bnd >> s) & 1u) {
          u32 rk = 0;
          for (u32 j = 0; j < nc; ++j) rk += (cand[w * 64 + j] > key_[s]) ? 1u : 0u;
          sel = (rk < need);
        }
      }
      selbits |= (sel ? 1u : 0u) << s;
    }
    bool badw = (__ballot(bad) != 0ull);
    if (!badw) {
      u32 selcnt = __popc(selbits);
      u32 incl = selcnt;
#pragma unroll
      for (int d = 1; d < 64; d <<= 1) {
        u32 o = __shfl_up(incl, d, 64);
        if (lane >= d) incl += o;
      }
      u32 off = incl - selcnt;       // lanes before me (rows ascending = lane-major)
      u32 k2 = 0;
#pragma unroll
      for (int s = 0; s < 16; ++s) {
        if ((selbits >> s) & 1u) {
          out[((size_t)b * KK + off + k2) * CC + c] =
              __uint_as_float(unflip_bits((u32)(key_[s] >> 32)));
          k2++;
        }
      }
      return;
    }
    bad = true;  // fall through to slow path (wave-uniform)
  }

  // ---- exact wave-local slow path (backstop; also force_slow) ----
  {
    u64 prev = ~0ull;
    u64 sel = 0;
    for (int r = 0; r < KK; ++r) {
      u64 local = 0;
      for (int tt = 0; tt < LL / 64; ++tt) {
        int l = tt * 64 + lane;
        float v = colp[(size_t)l * CC];
        u64 key = (((u64)flip_bits(__float_as_uint(v))) << 32) | (u32)l;
        if (key < prev) local = u64max(local, key);
      }
#pragma unroll
      for (int mm2 = 32; mm2 > 0; mm2 >>= 1) local = u64max(local, __shfl_xor(local, mm2, 64));
      if (lane == r) sel = local;
      prev = local;
    }
    // re-key by (index, value), sort ASCENDING across wave -> original order
    u32 f = (u32)(sel >> 32);
    u32 l = (u32)sel;
    u64 s2 = (((u64)l) << 32) | f;
#pragma unroll
    for (int k = 2; k <= 64; k <<= 1) {
#pragma unroll
      for (int j = k >> 1; j > 0; j >>= 1) {
        u64 other = __shfl_xor(s2, j, 64);
        bool upper = (lane & j) != 0;
        bool ascb = ((lane & k) == 0);
        bool keepmax = ascb ? upper : !upper;
        u64 mx = (s2 > other) ? s2 : other;
        u64 mn = (s2 > other) ? other : s2;
        s2 = keepmax ? mx : mn;
      }
    }
    out[((size_t)b * KK + lane) * CC + c] = __uint_as_float(unflip_bits((u32)s2));
  }
}

extern "C" void kernel_launch(void* const* d_in, const int* in_sizes, int n_in,
                              void* d_out, int out_size, void* d_ws, size_t ws_size,
                              hipStream_t stream) {
  const float* x = (const float*)d_in[0];
  float* out = (float*)d_out;
  const size_t need = (size_t)BB * LCH * CC * sizeof(u32);  // 8 MB of bitmasks
  if (d_ws != nullptr && ws_size >= need) {
    u32* bm = (u32*)d_ws;
    kbitmask<<<BB * LCH, 128, 0, stream>>>(x, bm);
    kselect<<<(BB * CC) / 16, 1024, 0, stream>>>(x, bm, out, 0);
  } else {
    kselect<<<(BB * CC) / 16, 1024, 0, stream>>>(x, nullptr, out, 1);
  }
}